// Round 4
// baseline (138.222 us; speedup 1.0000x reference)
//
#include <hip/hip_runtime.h>

// PlaceFields: out = sum_{n,p} (scales[n]*exp(-0.5*q(n,p)) - real[n,p])^2
// N=512, P=256*256. Memory-bound on `real` (134 MB f32, read once). Floor ~21us.
//
// R4: R2 main body (plain cached loads — nt-load regressed by killing L3
// residency) + fused final reduction via last-block-done ticket counter
// (removes the second kernel dispatch). Counter zeroed by a 4-byte
// hipMemsetAsync node each call (d_ws is poisoned once, never re-poisoned).

#define NPIX   65536
#define CPX    2048
#define GN     8
#define BLOCK  256
#define PPT    (CPX / BLOCK)   // 8 pixels per thread

__global__ __launch_bounds__(BLOCK) void pf_fused(
    const float* __restrict__ coords,      // (P,2)
    const float* __restrict__ real,        // (N,P)
    const float* __restrict__ means,       // (N,2)
    const float* __restrict__ cid,         // (N,2)
    const float* __restrict__ cod,         // (N,1)
    const float* __restrict__ scales,      // (N,1)
    float* __restrict__ partial,           // (nblocks)
    unsigned int* __restrict__ counter,    // 1, pre-zeroed per call
    float* __restrict__ out,               // 1
    int nblocks)
{
    const int nchunks = NPIX / CPX;                 // 32
    const int n0 = (blockIdx.x / nchunks) * GN;
    const int p0 = (blockIdx.x % nchunks) * CPX;
    const int tid = threadIdx.x;
    const int pb  = p0 + tid * PPT;

    // 8 pixels of coords -> registers, once per block (normal cached loads).
    const float4 c0 = *reinterpret_cast<const float4*>(coords + 2 * pb);
    const float4 c1 = *reinterpret_cast<const float4*>(coords + 2 * pb + 4);
    const float4 c2 = *reinterpret_cast<const float4*>(coords + 2 * pb + 8);
    const float4 c3 = *reinterpret_cast<const float4*>(coords + 2 * pb + 12);

    float px[PPT]  = {c0.x, c0.z, c1.x, c1.z, c2.x, c2.z, c3.x, c3.z};
    float py[PPT]  = {c0.y, c0.w, c1.y, c1.w, c2.y, c2.w, c3.y, c3.w};
    float pxx[PPT], pxy[PPT], pyy[PPT];
    #pragma unroll
    for (int j = 0; j < PPT; ++j) {
        pxx[j] = px[j] * px[j];
        pxy[j] = px[j] * py[j];
        pyy[j] = py[j] * py[j];
    }

    const float K = -0.72134752044448169f;   // -0.5 / ln(2)

    float acc = 0.0f;
    #pragma unroll 2
    for (int g = 0; g < GN; ++g) {
        const int n = n0 + g;
        const float mx = means[2 * n];
        const float my = means[2 * n + 1];
        const float a  = cid[2 * n];
        const float cc = cid[2 * n + 1];
        const float bb = cod[n];
        const float s  = scales[n];

        const float A  = K * a;
        const float Bh = K * bb;
        const float C  = K * cc;
        const float cB = 2.0f * Bh;
        const float cE = -2.0f * (A * mx + Bh * my);
        const float cF = -2.0f * (Bh * mx + C * my);
        const float cG = A * mx * mx + cB * mx * my + C * my * my
                       + __builtin_amdgcn_logf(s);   // v_log_f32 = log2

        const float* __restrict__ rp = real + (size_t)n * NPIX + pb;
        const float4 r0 = *reinterpret_cast<const float4*>(rp);
        const float4 r1 = *reinterpret_cast<const float4*>(rp + 4);
        const float rr[PPT] = {r0.x, r0.y, r0.z, r0.w, r1.x, r1.y, r1.z, r1.w};

        #pragma unroll
        for (int j = 0; j < PPT; ++j) {
            const float t = fmaf(A,  pxx[j],
                            fmaf(cB, pxy[j],
                            fmaf(C,  pyy[j],
                            fmaf(cE, px[j],
                            fmaf(cF, py[j], cG)))));
            const float pred = __builtin_amdgcn_exp2f(t);
            const float d = pred - rr[j];
            acc = fmaf(d, d, acc);
        }
    }

    // wave reduce (64 lanes) then cross-wave via LDS
    #pragma unroll
    for (int off = 32; off > 0; off >>= 1)
        acc += __shfl_down(acc, off, 64);

    __shared__ float wsum[BLOCK / 64];
    __shared__ int amLast;
    const int lane = tid & 63;
    const int wid  = tid >> 6;
    if (lane == 0) wsum[wid] = acc;
    __syncthreads();

    if (tid == 0) {
        const float t = wsum[0] + wsum[1] + wsum[2] + wsum[3];
        // release-store this block's partial, then take a ticket (agent scope:
        // crosses the per-XCD L2s via the device-coherent point)
        __hip_atomic_store(&partial[blockIdx.x], t,
                           __ATOMIC_RELEASE, __HIP_MEMORY_SCOPE_AGENT);
        const unsigned old = __hip_atomic_fetch_add(counter, 1u,
                           __ATOMIC_ACQ_REL, __HIP_MEMORY_SCOPE_AGENT);
        amLast = (old == (unsigned)(nblocks - 1));
    }
    __syncthreads();

    if (amLast) {
        // last block to finish: reduce all partials (fixed order -> deterministic)
        float a2 = 0.0f;
        for (int i = tid; i < nblocks; i += BLOCK)
            a2 += __hip_atomic_load(&partial[i],
                                    __ATOMIC_ACQUIRE, __HIP_MEMORY_SCOPE_AGENT);
        #pragma unroll
        for (int off = 32; off > 0; off >>= 1)
            a2 += __shfl_down(a2, off, 64);
        if (lane == 0) wsum[wid] = a2;
        __syncthreads();
        if (tid == 0)
            out[0] = wsum[0] + wsum[1] + wsum[2] + wsum[3];
    }
}

extern "C" void kernel_launch(void* const* d_in, const int* in_sizes, int n_in,
                              void* d_out, int out_size, void* d_ws, size_t ws_size,
                              hipStream_t stream) {
    const float* coords = (const float*)d_in[0];
    const float* real   = (const float*)d_in[1];
    const float* means  = (const float*)d_in[2];
    const float* cid    = (const float*)d_in[3];
    const float* cod    = (const float*)d_in[4];
    const float* scales = (const float*)d_in[5];
    float* out = (float*)d_out;

    const int N = in_sizes[2] / 2;                    // 512
    const int nblocks = (N / GN) * (NPIX / CPX);      // 64 * 32 = 2048

    unsigned int* counter = (unsigned int*)d_ws;                  // 4 B
    float* partial = (float*)((char*)d_ws + 256);                 // 8 KB

    hipMemsetAsync(counter, 0, sizeof(unsigned int), stream);

    pf_fused<<<dim3(nblocks), dim3(BLOCK), 0, stream>>>(
        coords, real, means, cid, cod, scales, partial, counter, out, nblocks);
}

// Round 5
// 48.658 us; speedup vs baseline: 2.8407x; 2.8407x over previous
//
#include <hip/hip_runtime.h>

// PlaceFields: out = sum_{n,p} (scales[n]*exp(-0.5*q(n,p)) - real[n,p])^2
// N=512, P=256*256. Memory-bound on `real` (134 MB f32, read once).
//
// R5: R2 main body (known-good 31.6us) + fused last-block reduction, but with
// RELAXED agent-scope atomics only. R4's ACQ_REL/ACQUIRE at agent scope emitted
// buffer_wbl2/buffer_inv per block (2048 L2 nukes -> 138us). Here:
//   store partial (relaxed, agent = device-coherent sc-flagged store)
//   s_waitcnt vmcnt(0)            (partial at coherence point before ticket)
//   fetch_add counter (relaxed, agent)  -- no fence instructions
// Last block reads partials with relaxed agent-scope loads (bypass stale L2).
// Fixed reduce order -> deterministic. Counter zeroed via 4-byte memset node.

#define NPIX   65536
#define CPX    2048
#define GN     8
#define BLOCK  256
#define PPT    (CPX / BLOCK)   // 8 pixels per thread

__global__ __launch_bounds__(BLOCK) void pf_fused(
    const float* __restrict__ coords,      // (P,2)
    const float* __restrict__ real,        // (N,P)
    const float* __restrict__ means,       // (N,2)
    const float* __restrict__ cid,         // (N,2)
    const float* __restrict__ cod,         // (N,1)
    const float* __restrict__ scales,      // (N,1)
    float* __restrict__ partial,           // (nblocks)
    unsigned int* __restrict__ counter,    // 1, pre-zeroed per call
    float* __restrict__ out,               // 1
    int nblocks)
{
    const int nchunks = NPIX / CPX;                 // 32
    const int n0 = (blockIdx.x / nchunks) * GN;
    const int p0 = (blockIdx.x % nchunks) * CPX;
    const int tid = threadIdx.x;
    const int pb  = p0 + tid * PPT;

    // 8 pixels of coords -> registers, once per block (normal cached loads).
    const float4 c0 = *reinterpret_cast<const float4*>(coords + 2 * pb);
    const float4 c1 = *reinterpret_cast<const float4*>(coords + 2 * pb + 4);
    const float4 c2 = *reinterpret_cast<const float4*>(coords + 2 * pb + 8);
    const float4 c3 = *reinterpret_cast<const float4*>(coords + 2 * pb + 12);

    float px[PPT]  = {c0.x, c0.z, c1.x, c1.z, c2.x, c2.z, c3.x, c3.z};
    float py[PPT]  = {c0.y, c0.w, c1.y, c1.w, c2.y, c2.w, c3.y, c3.w};
    float pxx[PPT], pxy[PPT], pyy[PPT];
    #pragma unroll
    for (int j = 0; j < PPT; ++j) {
        pxx[j] = px[j] * px[j];
        pxy[j] = px[j] * py[j];
        pyy[j] = py[j] * py[j];
    }

    const float K = -0.72134752044448169f;   // -0.5 / ln(2)

    float acc = 0.0f;
    #pragma unroll 2
    for (int g = 0; g < GN; ++g) {
        const int n = n0 + g;
        const float mx = means[2 * n];
        const float my = means[2 * n + 1];
        const float a  = cid[2 * n];
        const float cc = cid[2 * n + 1];
        const float bb = cod[n];
        const float s  = scales[n];

        const float A  = K * a;
        const float Bh = K * bb;
        const float C  = K * cc;
        const float cB = 2.0f * Bh;
        const float cE = -2.0f * (A * mx + Bh * my);
        const float cF = -2.0f * (Bh * mx + C * my);
        const float cG = A * mx * mx + cB * mx * my + C * my * my
                       + __builtin_amdgcn_logf(s);   // v_log_f32 = log2

        const float* __restrict__ rp = real + (size_t)n * NPIX + pb;
        const float4 r0 = *reinterpret_cast<const float4*>(rp);
        const float4 r1 = *reinterpret_cast<const float4*>(rp + 4);
        const float rr[PPT] = {r0.x, r0.y, r0.z, r0.w, r1.x, r1.y, r1.z, r1.w};

        #pragma unroll
        for (int j = 0; j < PPT; ++j) {
            const float t = fmaf(A,  pxx[j],
                            fmaf(cB, pxy[j],
                            fmaf(C,  pyy[j],
                            fmaf(cE, px[j],
                            fmaf(cF, py[j], cG)))));
            const float pred = __builtin_amdgcn_exp2f(t);
            const float d = pred - rr[j];
            acc = fmaf(d, d, acc);
        }
    }

    // wave reduce (64 lanes) then cross-wave via LDS
    #pragma unroll
    for (int off = 32; off > 0; off >>= 1)
        acc += __shfl_down(acc, off, 64);

    __shared__ float wsum[BLOCK / 64];
    __shared__ int amLast;
    const int lane = tid & 63;
    const int wid  = tid >> 6;
    if (lane == 0) wsum[wid] = acc;
    __syncthreads();

    if (tid == 0) {
        const float t = wsum[0] + wsum[1] + wsum[2] + wsum[3];
        // device-coherent store of this block's partial (no fence instrs)
        __hip_atomic_store(&partial[blockIdx.x], t,
                           __ATOMIC_RELAXED, __HIP_MEMORY_SCOPE_AGENT);
        // ensure the store reached the coherence point before taking a ticket
        asm volatile("s_waitcnt vmcnt(0)" ::: "memory");
        const unsigned old = __hip_atomic_fetch_add(counter, 1u,
                           __ATOMIC_RELAXED, __HIP_MEMORY_SCOPE_AGENT);
        amLast = (old == (unsigned)(nblocks - 1));
    }
    __syncthreads();

    if (amLast) {
        // last block: reduce all partials with device-coherent loads,
        // fixed order -> deterministic result
        float a2 = 0.0f;
        for (int i = tid; i < nblocks; i += BLOCK)
            a2 += __hip_atomic_load(&partial[i],
                                    __ATOMIC_RELAXED, __HIP_MEMORY_SCOPE_AGENT);
        #pragma unroll
        for (int off = 32; off > 0; off >>= 1)
            a2 += __shfl_down(a2, off, 64);
        if (lane == 0) wsum[wid] = a2;
        __syncthreads();
        if (tid == 0)
            out[0] = wsum[0] + wsum[1] + wsum[2] + wsum[3];
    }
}

extern "C" void kernel_launch(void* const* d_in, const int* in_sizes, int n_in,
                              void* d_out, int out_size, void* d_ws, size_t ws_size,
                              hipStream_t stream) {
    const float* coords = (const float*)d_in[0];
    const float* real   = (const float*)d_in[1];
    const float* means  = (const float*)d_in[2];
    const float* cid    = (const float*)d_in[3];
    const float* cod    = (const float*)d_in[4];
    const float* scales = (const float*)d_in[5];
    float* out = (float*)d_out;

    const int N = in_sizes[2] / 2;                    // 512
    const int nblocks = (N / GN) * (NPIX / CPX);      // 64 * 32 = 2048

    unsigned int* counter = (unsigned int*)d_ws;                  // 4 B
    float* partial = (float*)((char*)d_ws + 256);                 // 8 KB

    hipMemsetAsync(counter, 0, sizeof(unsigned int), stream);

    pf_fused<<<dim3(nblocks), dim3(BLOCK), 0, stream>>>(
        coords, real, means, cid, cod, scales, partial, counter, out, nblocks);
}

// Round 6
// 28.835 us; speedup vs baseline: 4.7936x; 1.6875x over previous
//
#include <hip/hip_runtime.h>

// PlaceFields: out = sum_{n,p} (scales[n]*exp(-0.5*q(n,p)) - real[n,p])^2
// N=512, P=256*256. Memory-bound on `real` (134 MB f32, read once).
//
// R6: R2 two-kernel structure (fusion regressed twice: R4 acq_rel fences
// -> 138us, R5 relaxed agent atomics -> 49us). Single change vs R2: fully
// unrolled gaussian loop with explicit 1-deep prefetch using PLAIN CACHED
// loads (R3's regression is attributed to the nontemporal hint killing L3
// residency, not the pipeline). 4 float4 loads in flight per lane.

#define NPIX   65536
#define CPX    2048
#define GN     8
#define BLOCK  256
#define PPT    (CPX / BLOCK)   // 8 pixels per thread

__global__ __launch_bounds__(BLOCK) void pf_main(
    const float* __restrict__ coords,      // (P,2)
    const float* __restrict__ real,        // (N,P)
    const float* __restrict__ means,       // (N,2)
    const float* __restrict__ cid,         // (N,2)
    const float* __restrict__ cod,         // (N,1)
    const float* __restrict__ scales,      // (N,1)
    float* __restrict__ partial)           // (gridDim.x)
{
    const int nchunks = NPIX / CPX;                 // 32
    const int n0 = (blockIdx.x / nchunks) * GN;
    const int p0 = (blockIdx.x % nchunks) * CPX;
    const int tid = threadIdx.x;
    const int pb  = p0 + tid * PPT;

    // 8 pixels of coords -> registers, once per block (cached loads).
    const float4 c0 = *reinterpret_cast<const float4*>(coords + 2 * pb);
    const float4 c1 = *reinterpret_cast<const float4*>(coords + 2 * pb + 4);
    const float4 c2 = *reinterpret_cast<const float4*>(coords + 2 * pb + 8);
    const float4 c3 = *reinterpret_cast<const float4*>(coords + 2 * pb + 12);

    float px[PPT]  = {c0.x, c0.z, c1.x, c1.z, c2.x, c2.z, c3.x, c3.z};
    float py[PPT]  = {c0.y, c0.w, c1.y, c1.w, c2.y, c2.w, c3.y, c3.w};
    float pxx[PPT], pxy[PPT], pyy[PPT];
    #pragma unroll
    for (int j = 0; j < PPT; ++j) {
        pxx[j] = px[j] * px[j];
        pxy[j] = px[j] * py[j];
        pyy[j] = py[j] * py[j];
    }

    const float K = -0.72134752044448169f;   // -0.5 / ln(2)

    const float* __restrict__ rpb = real + (size_t)n0 * NPIX + pb;

    // prefetch gaussian 0's real tile (plain cached loads)
    float4 r0 = *reinterpret_cast<const float4*>(rpb);
    float4 r1 = *reinterpret_cast<const float4*>(rpb + 4);

    float acc = 0.0f;
    #pragma unroll
    for (int g = 0; g < GN; ++g) {
        const int n = n0 + g;
        const float mx = means[2 * n];
        const float my = means[2 * n + 1];
        const float a  = cid[2 * n];
        const float cc = cid[2 * n + 1];
        const float bb = cod[n];
        const float s  = scales[n];

        const float A  = K * a;
        const float Bh = K * bb;
        const float C  = K * cc;
        const float cB = 2.0f * Bh;
        const float cE = -2.0f * (A * mx + Bh * my);
        const float cF = -2.0f * (Bh * mx + C * my);
        const float cG = A * mx * mx + cB * mx * my + C * my * my
                       + __builtin_amdgcn_logf(s);   // v_log_f32 = log2

        // issue next gaussian's loads before computing the current one
        float4 s0, s1;
        if (g + 1 < GN) {
            const float* rn = rpb + (size_t)(g + 1) * NPIX;
            s0 = *reinterpret_cast<const float4*>(rn);
            s1 = *reinterpret_cast<const float4*>(rn + 4);
        }

        const float rr[PPT] = {r0.x, r0.y, r0.z, r0.w, r1.x, r1.y, r1.z, r1.w};

        #pragma unroll
        for (int j = 0; j < PPT; ++j) {
            const float t = fmaf(A,  pxx[j],
                            fmaf(cB, pxy[j],
                            fmaf(C,  pyy[j],
                            fmaf(cE, px[j],
                            fmaf(cF, py[j], cG)))));
            const float pred = __builtin_amdgcn_exp2f(t);
            const float d = pred - rr[j];
            acc = fmaf(d, d, acc);
        }

        r0 = s0; r1 = s1;
    }

    // wave reduce (64 lanes) then cross-wave via LDS
    #pragma unroll
    for (int off = 32; off > 0; off >>= 1)
        acc += __shfl_down(acc, off, 64);

    __shared__ float wsum[BLOCK / 64];
    const int lane = tid & 63;
    const int wid  = tid >> 6;
    if (lane == 0) wsum[wid] = acc;
    __syncthreads();
    if (tid == 0)
        partial[blockIdx.x] = wsum[0] + wsum[1] + wsum[2] + wsum[3];
}

__global__ __launch_bounds__(BLOCK) void pf_reduce(
    const float* __restrict__ partial, int n, float* __restrict__ out)
{
    float acc = 0.0f;
    for (int i = threadIdx.x; i < n; i += BLOCK) acc += partial[i];
    #pragma unroll
    for (int off = 32; off > 0; off >>= 1)
        acc += __shfl_down(acc, off, 64);
    __shared__ float wsum[BLOCK / 64];
    const int lane = threadIdx.x & 63;
    const int wid  = threadIdx.x >> 6;
    if (lane == 0) wsum[wid] = acc;
    __syncthreads();
    if (threadIdx.x == 0) out[0] = wsum[0] + wsum[1] + wsum[2] + wsum[3];
}

extern "C" void kernel_launch(void* const* d_in, const int* in_sizes, int n_in,
                              void* d_out, int out_size, void* d_ws, size_t ws_size,
                              hipStream_t stream) {
    const float* coords = (const float*)d_in[0];
    const float* real   = (const float*)d_in[1];
    const float* means  = (const float*)d_in[2];
    const float* cid    = (const float*)d_in[3];
    const float* cod    = (const float*)d_in[4];
    const float* scales = (const float*)d_in[5];
    float* out = (float*)d_out;

    const int N = in_sizes[2] / 2;                    // 512
    const int nblocks = (N / GN) * (NPIX / CPX);      // 64 * 32 = 2048
    float* partial = (float*)d_ws;                    // 8 KB

    pf_main<<<dim3(nblocks), dim3(BLOCK), 0, stream>>>(coords, real, means, cid,
                                                       cod, scales, partial);
    pf_reduce<<<dim3(1), dim3(BLOCK), 0, stream>>>(partial, nblocks, out);
}